// Round 8
// baseline (134.383 us; speedup 1.0000x reference)
//
#include <hip/hip_runtime.h>
#include <math.h>

// Problem constants: B=32, N_SOURCES=262144, H=W=256
#define BATCH 32
#define NSRC  262144
#define HH    256
#define WW    256
#define HW    (HH * WW)
#define NBLK  16                 // partial-reduce blocks per batch

// ---------- binned path (R8: single-pass scatter, per-block segments) ----------
// History: f32 LDS atomicAdd lowers to a CAS loop (R0-R3 accum pinned at 48us
// invariant to occupancy/MLP; R4 u32 fixed-point -> native ds_add_u32, -42us).
// R6 measured global scattered u32 atomics at ~32B write/RMW, 900 GB/s -> the
// arena+LDS-accumulate structure is ~9x better than fused global atomics.
// R5 (write coalescing) hurt; R7 (atomic vs ballot ranking) neutral => scatter
// cost is its two-phase structure, not ranking or store pattern.
// R8: each scatter block owns arena segment [block][16][CAP_PB]; items stored
// immediately after ds_add_rtn rank. No cursors, no barriers in the hot path,
// no ent/meta register arrays. cnt_tab[block][16] written once at block end.
#define ZBANDS 16
#define ZBAND_PIX (HW / ZBANDS)    // 4096 px -> 16 KB acc LDS
#define NB_SCAT 64                 // scatter blocks per batch (4096 items each)
#define CAP_PB  400                // per-block per-bin capacity (mean 256, +9sd)
#define SPILL_CAP 131072
#define FIX_SCALE 524288.0f        // 2^19
#define FIX_INV   (1.0f / 524288.0f)
//   [0, 8192)        float4 partials[BATCH][NBLK]
//   [8192, 8196)     u32 spill_cnt
//   [16384, 147456)  u32 cnt_tab[BATCH*NB_SCAT][ZBANDS]   (128 KB)
//   [147456, +1MB)   uint2 spill[SPILL_CAP]
//   [1196032, ...)   u32 arena[BATCH*NB_SCAT][ZBANDS][CAP_PB] (52.4 MB)
#define WS_SPCNT_OFF  8192
#define WS_CNTTAB_OFF 16384
#define WS_SPILL_OFF  (WS_CNTTAB_OFF + BATCH * NB_SCAT * ZBANDS * 4)
#define WS_ARENA_OFF  (WS_SPILL_OFF + SPILL_CAP * 8)
#define WS_BYTES      (WS_ARENA_OFF + (size_t)BATCH * NB_SCAT * ZBANDS * CAP_PB * 4)

#define FB_BANDS 8
#define FB_BAND_PIX (HW / FB_BANDS)

// ---------- Kernel A: per-batch bounding-box partials (+ zero spill_cnt) ----------
__global__ void box_kernel(const float* __restrict__ spatial,
                           float4* __restrict__ partials,
                           unsigned int* __restrict__ zero_tab,  // may be null
                           int zero_n) {
    const int b   = blockIdx.y;
    const int blk = blockIdx.x;
    const int tid = threadIdx.x;  // 0..255

    if (zero_tab && blk == 0 && b == 0) {
        for (int j = tid; j < zero_n; j += 256) zero_tab[j] = 0u;
    }

    const int chunk = HW / NBLK;  // 4096
    const float* xs = spatial + (size_t)b * 2 * HW + (size_t)blk * chunk;
    const float* ys = xs + HW;

    float xmn = 1e30f, xmx = -1e30f, ymn = 1e30f, ymx = -1e30f;
    const float4* xs4 = (const float4*)xs;
    const float4* ys4 = (const float4*)ys;
#pragma unroll
    for (int k = 0; k < 4; k++) {
        float4 vx = xs4[k * 256 + tid];
        float4 vy = ys4[k * 256 + tid];
        xmn = fminf(xmn, fminf(fminf(vx.x, vx.y), fminf(vx.z, vx.w)));
        xmx = fmaxf(xmx, fmaxf(fmaxf(vx.x, vx.y), fmaxf(vx.z, vx.w)));
        ymn = fminf(ymn, fminf(fminf(vy.x, vy.y), fminf(vy.z, vy.w)));
        ymx = fmaxf(ymx, fmaxf(fmaxf(vy.x, vy.y), fmaxf(vy.z, vy.w)));
    }
#pragma unroll
    for (int off = 32; off > 0; off >>= 1) {
        xmn = fminf(xmn, __shfl_down(xmn, off));
        xmx = fmaxf(xmx, __shfl_down(xmx, off));
        ymn = fminf(ymn, __shfl_down(ymn, off));
        ymx = fmaxf(ymx, __shfl_down(ymx, off));
    }
    __shared__ float4 s[4];
    if ((tid & 63) == 0) s[tid >> 6] = make_float4(xmn, xmx, ymn, ymx);
    __syncthreads();
    if (tid == 0) {
        float4 r = s[0];
#pragma unroll
        for (int wv = 1; wv < 4; wv++) {
            float4 t = s[wv];
            r.x = fminf(r.x, t.x); r.y = fmaxf(r.y, t.y);
            r.z = fminf(r.z, t.z); r.w = fmaxf(r.w, t.w);
        }
        partials[b * NBLK + blk] = r;
    }
}

__device__ __forceinline__ float4 fold_box(const float4* __restrict__ partials,
                                           int b, int tid, float4* sbox) {
    if (tid < 64) {
        float4 p = make_float4(1e30f, -1e30f, 1e30f, -1e30f);
        if (tid < NBLK) p = partials[b * NBLK + tid];
        float xmn = p.x, xmx = p.y, ymn = p.z, ymx = p.w;
#pragma unroll
        for (int off = 8; off > 0; off >>= 1) {
            xmn = fminf(xmn, __shfl_down(xmn, off));
            xmx = fmaxf(xmx, __shfl_down(xmx, off));
            ymn = fminf(ymn, __shfl_down(ymn, off));
            ymx = fmaxf(ymx, __shfl_down(ymx, off));
        }
        if (tid == 0) *sbox = make_float4(xmn, xmx, ymn, ymx);
    }
    __syncthreads();
    return *sbox;
}

// Verified reference pipeline (R8): reciprocal-multiply, correctly-rounded f32,
// half-even rounding, clip to [0,255].
__device__ __forceinline__ int route_of(float cx, float cy, float xmin,
                                        float ymin, float invx, float invy) {
    const float nx = __fmul_rn(__fsub_rn(cx, xmin), invx);
    const float ny = __fmul_rn(__fsub_rn(cy, ymin), invy);
    int px = (int)rintf(__fmul_rn(nx, 255.0f));
    int py = (int)rintf(__fmul_rn(ny, 255.0f));
    px = px < 0 ? 0 : (px > 255 ? 255 : px);
    py = py < 0 ? 0 : (py > 255 ? 255 : py);
    return py * WW + px;
}

// ---------- single-pass scatter: route -> ds_add_rtn rank -> immediate store ----------
__global__ __launch_bounds__(256) void scatter_seg_kernel(
    const float* __restrict__ point_rates, const float2* __restrict__ coords,
    const float4* __restrict__ partials, unsigned int* __restrict__ arena,
    unsigned int* __restrict__ cnt_tab, unsigned int* __restrict__ spill_cnt,
    uint2* __restrict__ spill) {
    const int b   = blockIdx.y;
    const int blk = blockIdx.x;   // 0..NB_SCAT-1
    const int tid = threadIdx.x;
    __shared__ float4 sbox;
    __shared__ unsigned int cnt[ZBANDS];  // block-local bin counts

    if (tid < ZBANDS) cnt[tid] = 0u;  // covered by fold_box's barrier
    const float4 box = fold_box(partials, b, tid, &sbox);
    const float xmin = box.x, xmax = box.y, ymin = box.z, ymax = box.w;
    const float invx = __fdiv_rn(1.0f, __fsub_rn(xmax, xmin));
    const float invy = __fdiv_rn(1.0f, __fsub_rn(ymax, ymin));

    const float* prb = point_rates + (size_t)b * NSRC;
    const int base = blk * 4096;
    // this block's private arena segment: [ZBANDS][CAP_PB]
    unsigned int* seg =
        arena + ((size_t)b * NB_SCAT + blk) * ZBANDS * CAP_PB;

#pragma unroll
    for (int kk = 0; kk < 16; kk += 4) {
        float2 c0, c1, c2, c3;
        float  p0, p1, p2, p3;
        {
            const int i0 = base + (kk + 0) * 256 + tid;
            const int i1 = base + (kk + 1) * 256 + tid;
            const int i2 = base + (kk + 2) * 256 + tid;
            const int i3 = base + (kk + 3) * 256 + tid;
            c0 = coords[i0]; c1 = coords[i1];
            c2 = coords[i2]; c3 = coords[i3];
            p0 = prb[i0]; p1 = prb[i1]; p2 = prb[i2]; p3 = prb[i3];
        }
        asm volatile(""
                     : "+v"(c0.x), "+v"(c0.y), "+v"(p0),
                       "+v"(c1.x), "+v"(c1.y), "+v"(p1),
                       "+v"(c2.x), "+v"(c2.y), "+v"(p2),
                       "+v"(c3.x), "+v"(c3.y), "+v"(p3));
#define DO_ONE(CC, PP)                                                       \
    {                                                                        \
        const bool valid = !(CC.x < xmin || CC.x > xmax ||                   \
                             CC.y < ymin || CC.y > ymax);                    \
        const int idx = route_of(CC.x, CC.y, xmin, ymin, invx, invy);        \
        const unsigned int fixed =                                           \
            (unsigned int)(__fmul_rn(PP, FIX_SCALE) + 0.5f);                 \
        const unsigned int e =                                               \
            (unsigned int)(idx & (ZBAND_PIX - 1)) | (fixed << 12);           \
        const int z = idx >> 12;                                             \
        if (valid) {                                                         \
            const unsigned int rank = atomicAdd(&cnt[z], 1u);                \
            if (rank < CAP_PB) {                                             \
                seg[(unsigned int)z * CAP_PB + rank] = e;                    \
            } else {                                                         \
                const unsigned int pos = atomicAdd(spill_cnt, 1u);           \
                if (pos < SPILL_CAP) {                                       \
                    const unsigned int pix =                                 \
                        ((unsigned int)z << 12) | (e & (ZBAND_PIX - 1));     \
                    const float prq = __fmul_rn((float)(e >> 12), FIX_INV);  \
                    spill[pos] = make_uint2(                                 \
                        ((unsigned int)b << 16) | pix,                       \
                        __float_as_uint(prq));                               \
                }                                                            \
            }                                                                \
        }                                                                    \
    }
        DO_ONE(c0, p0)
        DO_ONE(c1, p1)
        DO_ONE(c2, p2)
        DO_ONE(c3, p3)
#undef DO_ONE
    }
    __syncthreads();

    // publish per-bin counts (clamped to capacity for the accum reader)
    if (tid < ZBANDS) {
        unsigned int c = cnt[tid];
        cnt_tab[((size_t)b * NB_SCAT + blk) * ZBANDS + tid] =
            c < CAP_PB ? c : CAP_PB;
    }
}

// u32 fixed-point LDS accumulation (native ds_add_u32); grid (16,32), 1024
// threads = 16 waves; wave w drains segments blk = w, w+16, w+32, w+48.
__global__ __launch_bounds__(1024) void accum_g_kernel(
    const unsigned int* __restrict__ arena, const float* __restrict__ gia,
    const unsigned int* __restrict__ cnt_tab, float* __restrict__ out) {
    __shared__ unsigned int acc[ZBAND_PIX];  // 16 KB
    const int z    = blockIdx.x;
    const int b    = blockIdx.y;
    const int tid  = threadIdx.x;  // 0..1023
    const int wave = tid >> 6;
    const int lane = tid & 63;

    // issue long-latency epilogue gia read before the LDS work
    const float4* g4 =
        (const float4*)(gia + (size_t)b * HW + (size_t)z * ZBAND_PIX);
    float4 g = g4[tid];
    asm volatile("" : "+v"(g.x), "+v"(g.y), "+v"(g.z), "+v"(g.w));

    ((uint4*)acc)[tid] = make_uint4(0u, 0u, 0u, 0u);  // 4096 words
    __syncthreads();

    // entry = fixed20<<12 | pix12 ; accumulate fixed-point pr (g factored out)
#define DO_E(w)                                                              \
    atomicAdd(&acc[(w) & (ZBAND_PIX - 1)], (w) >> 12);
#pragma unroll
    for (int s = 0; s < NB_SCAT / 16; s++) {
        const int blk = wave + s * 16;
        const unsigned int n =
            cnt_tab[((size_t)b * NB_SCAT + blk) * ZBANDS + z];
        const unsigned int* seg =
            arena + (((size_t)b * NB_SCAT + blk) * ZBANDS + (unsigned)z) *
                        CAP_PB;
        const unsigned int n4 = n >> 2;  // ~64: one uint4 per lane typical
        for (unsigned int j = lane; j < n4; j += 64u) {
            const uint4 e = ((const uint4*)seg)[j];
            DO_E(e.x) DO_E(e.y) DO_E(e.z) DO_E(e.w)
        }
        for (unsigned int j = (n4 << 2) + lane; j < n; j += 64u) {
            DO_E(seg[j])
        }
    }
#undef DO_E
    __syncthreads();

    // out = acc * 2^-19 * g, coalesced direct store (block owns band)
    float4* o4 = (float4*)(out + (size_t)b * HW + (size_t)z * ZBAND_PIX);
    const uint4 a = ((const uint4*)acc)[tid];
    o4[tid] = make_float4(
        __fmul_rn(__fmul_rn((float)a.x, FIX_INV), g.x),
        __fmul_rn(__fmul_rn((float)a.y, FIX_INV), g.y),
        __fmul_rn(__fmul_rn((float)a.z, FIX_INV), g.z),
        __fmul_rn(__fmul_rn((float)a.w, FIX_INV), g.w));
}

__global__ void spill_kernel(const unsigned int* __restrict__ spill_cnt,
                             const uint2* __restrict__ spill,
                             const float* __restrict__ gia,
                             float* __restrict__ out) {
    unsigned int n = *spill_cnt;
    if (n > SPILL_CAP) n = SPILL_CAP;
    for (unsigned int j = blockIdx.x * 256 + threadIdx.x; j < n;
         j += gridDim.x * 256) {
        const uint2 e = spill[j];
        const unsigned int b = e.x >> 16;
        const unsigned int pix = e.x & 0xFFFFu;
        const float pr = __uint_as_float(e.y);
        atomicAdd(&out[(size_t)b * HW + pix],
                  __fmul_rn(pr, gia[(size_t)b * HW + pix]));
    }
}

// ================= FALLBACK (exact, small-ws) =================

__global__ __launch_bounds__(512) void accum_recompute_kernel(
    const float* __restrict__ point_rates, const float* __restrict__ gia,
    const float2* __restrict__ coords, const float4* __restrict__ partials,
    float* __restrict__ out) {
    __shared__ float acc[FB_BAND_PIX];
    __shared__ float4 sbox;
    const int z   = blockIdx.x;
    const int b   = blockIdx.y;
    const int tid = threadIdx.x;

    const float4 box = fold_box(partials, b, tid, &sbox);
    const float xmin = box.x, xmax = box.y, ymin = box.z, ymax = box.w;
    const float invx = __fdiv_rn(1.0f, __fsub_rn(xmax, xmin));
    const float invy = __fdiv_rn(1.0f, __fsub_rn(ymax, ymin));

    for (int j = tid; j < FB_BAND_PIX; j += 512) acc[j] = 0.f;
    __syncthreads();

    const float* prb = point_rates + (size_t)b * NSRC;
    const float* gb  = gia + (size_t)b * HW;
    const int lo = z * FB_BAND_PIX, hi = lo + FB_BAND_PIX;

    for (int i = tid; i < NSRC; i += 512) {
        const float2 c = coords[i];
        if (c.x < xmin || c.x > xmax || c.y < ymin || c.y > ymax) continue;
        const int idx = route_of(c.x, c.y, xmin, ymin, invx, invy);
        if (idx < lo || idx >= hi) continue;
        const float em = __fmul_rn(prb[i], gb[idx]);
        atomicAdd(&acc[idx - lo], em);
    }
    __syncthreads();

    float4* o4 = (float4*)(out + (size_t)b * HW + (size_t)z * FB_BAND_PIX);
    const float4* a4 = (const float4*)acc;
    for (int j = tid; j < FB_BAND_PIX / 4; j += 512) o4[j] = a4[j];
}

extern "C" void kernel_launch(void* const* d_in, const int* in_sizes, int n_in,
                              void* d_out, int out_size, void* d_ws, size_t ws_size,
                              hipStream_t stream) {
    const float* point_rates = (const float*)d_in[0];   // (B, NSRC)
    const float* spatial     = (const float*)d_in[1];   // (B, 2, H, W)
    const float* gia         = (const float*)d_in[2];   // (B, H, W)
    const float2* coords     = (const float2*)d_in[3];  // (NSRC, 2)
    float* out = (float*)d_out;                         // (B, 1, H, W)

    char* ws = (char*)d_ws;
    float4* partials = (float4*)ws;

    if (ws_size >= WS_BYTES) {
        unsigned int* spill_cnt = (unsigned int*)(ws + WS_SPCNT_OFF);
        unsigned int* cnt_tab   = (unsigned int*)(ws + WS_CNTTAB_OFF);
        uint2*        spill     = (uint2*)(ws + WS_SPILL_OFF);
        unsigned int* arena     = (unsigned int*)(ws + WS_ARENA_OFF);

        box_kernel<<<dim3(NBLK, BATCH), 256, 0, stream>>>(
            spatial, partials, spill_cnt, 1);
        scatter_seg_kernel<<<dim3(NB_SCAT, BATCH), 256, 0, stream>>>(
            point_rates, coords, partials, arena, cnt_tab, spill_cnt, spill);
        accum_g_kernel<<<dim3(ZBANDS, BATCH), 1024, 0, stream>>>(
            arena, gia, cnt_tab, out);
        spill_kernel<<<4, 256, 0, stream>>>(spill_cnt, spill, gia, out);
    } else {
        box_kernel<<<dim3(NBLK, BATCH), 256, 0, stream>>>(
            spatial, partials, nullptr, 0);
        accum_recompute_kernel<<<dim3(FB_BANDS, BATCH), 512, 0, stream>>>(
            point_rates, gia, coords, partials, out);
    }
}

// Round 9
// 124.344 us; speedup vs baseline: 1.0807x; 1.0807x over previous
//
#include <hip/hip_runtime.h>
#include <math.h>

// Problem constants: B=32, N_SOURCES=262144, H=W=256
#define BATCH 32
#define NSRC  262144
#define HH    256
#define WW    256
#define HW    (HH * WW)
#define NBLK  16                 // partial-reduce blocks per batch

// ---------- binned path (R9 = R7 revert + spill fused into accum) ----------
// History: f32 LDS atomicAdd lowers to a CAS loop (R0-R3 accum pinned at 48us
// invariant to occupancy/MLP; R4 u32 fixed-point -> native ds_add_u32, -42us).
// R6 measured global scattered u32 atomics at ~32B write/RMW, 900 GB/s -> the
// arena+LDS-accumulate structure is ~9x better than fused global atomics.
// Scatter structural experiments: R5 bin-sort coalescing +4us, R7 LDS-atomic
// ranking +-0, R8 per-block segments +10us => scatter is at its per-item
// load/route/rank/store floor (~35us); internal structure is irrelevant.
// R9: remove the spill_kernel launch (spill count is ~always 0); accum scans
// the spill list for its (b,z) before the epilogue. 4 launches -> 3.
#define ZBANDS 16
#define ZBAND_PIX (HW / ZBANDS)    // 4096 px -> 16 KB acc LDS
#define ZCAP   18432               // mean 16384, sd ~124; +16 sd headroom
#define SPILL_CAP 131072
#define FIX_SCALE 524288.0f        // 2^19
#define FIX_INV   (1.0f / 524288.0f)
//   [0, 8192)        float4 partials[BATCH][NBLK]
//   [8192, 10240)    u32 cursors[BATCH*ZBANDS] (512)
//   [10240, 10244)   u32 spill_cnt
//   [16384, +1MB)    uint2 spill[SPILL_CAP]
//   [1064960, ...)   u32 arena[BATCH*ZBANDS][ZCAP]  entry = fixed20<<12 | pix12
#define WS_ZCURS_OFF  8192
#define WS_ZSPCNT_OFF 10240
#define WS_ZSPILL_OFF 16384
#define WS_ZARENA_OFF (WS_ZSPILL_OFF + SPILL_CAP * 8)
#define WS_Z_BYTES    (WS_ZARENA_OFF + (size_t)BATCH * ZBANDS * ZCAP * 4)

#define FB_BANDS 8
#define FB_BAND_PIX (HW / FB_BANDS)

// ---------- Kernel A: per-batch bounding-box partials (+ zero small tables) ----------
__global__ void box_kernel(const float* __restrict__ spatial,
                           float4* __restrict__ partials,
                           unsigned int* __restrict__ zero_tab,  // may be null
                           int zero_n) {
    const int b   = blockIdx.y;
    const int blk = blockIdx.x;
    const int tid = threadIdx.x;  // 0..255

    if (zero_tab && blk == 0 && b == 0) {
        for (int j = tid; j < zero_n; j += 256) zero_tab[j] = 0u;
    }

    const int chunk = HW / NBLK;  // 4096
    const float* xs = spatial + (size_t)b * 2 * HW + (size_t)blk * chunk;
    const float* ys = xs + HW;

    float xmn = 1e30f, xmx = -1e30f, ymn = 1e30f, ymx = -1e30f;
    const float4* xs4 = (const float4*)xs;
    const float4* ys4 = (const float4*)ys;
#pragma unroll
    for (int k = 0; k < 4; k++) {
        float4 vx = xs4[k * 256 + tid];
        float4 vy = ys4[k * 256 + tid];
        xmn = fminf(xmn, fminf(fminf(vx.x, vx.y), fminf(vx.z, vx.w)));
        xmx = fmaxf(xmx, fmaxf(fmaxf(vx.x, vx.y), fmaxf(vx.z, vx.w)));
        ymn = fminf(ymn, fminf(fminf(vy.x, vy.y), fminf(vy.z, vy.w)));
        ymx = fmaxf(ymx, fmaxf(fmaxf(vy.x, vy.y), fmaxf(vy.z, vy.w)));
    }
#pragma unroll
    for (int off = 32; off > 0; off >>= 1) {
        xmn = fminf(xmn, __shfl_down(xmn, off));
        xmx = fmaxf(xmx, __shfl_down(xmx, off));
        ymn = fminf(ymn, __shfl_down(ymn, off));
        ymx = fmaxf(ymx, __shfl_down(ymx, off));
    }
    __shared__ float4 s[4];
    if ((tid & 63) == 0) s[tid >> 6] = make_float4(xmn, xmx, ymn, ymx);
    __syncthreads();
    if (tid == 0) {
        float4 r = s[0];
#pragma unroll
        for (int wv = 1; wv < 4; wv++) {
            float4 t = s[wv];
            r.x = fminf(r.x, t.x); r.y = fmaxf(r.y, t.y);
            r.z = fminf(r.z, t.z); r.w = fmaxf(r.w, t.w);
        }
        partials[b * NBLK + blk] = r;
    }
}

__device__ __forceinline__ float4 fold_box(const float4* __restrict__ partials,
                                           int b, int tid, float4* sbox) {
    if (tid < 64) {
        float4 p = make_float4(1e30f, -1e30f, 1e30f, -1e30f);
        if (tid < NBLK) p = partials[b * NBLK + tid];
        float xmn = p.x, xmx = p.y, ymn = p.z, ymx = p.w;
#pragma unroll
        for (int off = 8; off > 0; off >>= 1) {
            xmn = fminf(xmn, __shfl_down(xmn, off));
            xmx = fmaxf(xmx, __shfl_down(xmx, off));
            ymn = fminf(ymn, __shfl_down(ymn, off));
            ymx = fmaxf(ymx, __shfl_down(ymx, off));
        }
        if (tid == 0) *sbox = make_float4(xmn, xmx, ymn, ymx);
    }
    __syncthreads();
    return *sbox;
}

// Verified reference pipeline (R8): reciprocal-multiply, correctly-rounded f32,
// half-even rounding, clip to [0,255].
__device__ __forceinline__ int route_of(float cx, float cy, float xmin,
                                        float ymin, float invx, float invy) {
    const float nx = __fmul_rn(__fsub_rn(cx, xmin), invx);
    const float ny = __fmul_rn(__fsub_rn(cy, ymin), invy);
    int px = (int)rintf(__fmul_rn(nx, 255.0f));
    int py = (int)rintf(__fmul_rn(ny, 255.0f));
    px = px < 0 ? 0 : (px > 255 ? 255 : px);
    py = py < 0 ? 0 : (py > 255 ? 255 : py);
    return py * WW + px;
}

// ================= BINNED PATH =================
// Scatter: block-local ranks via native LDS ds_add_rtn_u32 (R7);
//          entry = fixed20(pr)<<12 | pix12.
// Accum:   native u32 LDS atomicAdd of fixed-point pr (g factored out);
//          drains the (rare) spill list for its (b,z) before the epilogue.

__global__ __launch_bounds__(256) void scatter_lds_kernel(
    const float* __restrict__ point_rates, const float2* __restrict__ coords,
    const float4* __restrict__ partials, unsigned int* __restrict__ cursors,
    unsigned int* __restrict__ arena, unsigned int* __restrict__ spill_cnt,
    uint2* __restrict__ spill) {
    const int b   = blockIdx.y;
    const int tid = threadIdx.x;
    __shared__ float4 sbox;
    __shared__ unsigned int cnt[ZBANDS];    // block-local bin counts
    __shared__ unsigned int gbase[ZBANDS];  // global arena base per bin

    if (tid < ZBANDS) cnt[tid] = 0u;  // covered by fold_box's barrier
    const float4 box = fold_box(partials, b, tid, &sbox);
    const float xmin = box.x, xmax = box.y, ymin = box.z, ymax = box.w;
    const float invx = __fdiv_rn(1.0f, __fsub_rn(xmax, xmin));
    const float invy = __fdiv_rn(1.0f, __fsub_rn(ymax, ymin));

    const float* prb = point_rates + (size_t)b * NSRC;
    const int base = blockIdx.x * 4096;

    unsigned int ent[16];
    unsigned int meta[16];  // (z<<16)|block_rank, or 0xFFFFFFFF if skipped

    // Phase 1: route + rank. Iterations are independent (no ballot chain);
    // loads grouped 4-wide and pinned for MLP (R3 idiom).
#pragma unroll
    for (int kk = 0; kk < 16; kk += 4) {
        float2 c0, c1, c2, c3;
        float  p0, p1, p2, p3;
        {
            const int i0 = base + (kk + 0) * 256 + tid;
            const int i1 = base + (kk + 1) * 256 + tid;
            const int i2 = base + (kk + 2) * 256 + tid;
            const int i3 = base + (kk + 3) * 256 + tid;
            c0 = coords[i0]; c1 = coords[i1];
            c2 = coords[i2]; c3 = coords[i3];
            p0 = prb[i0]; p1 = prb[i1]; p2 = prb[i2]; p3 = prb[i3];
        }
        asm volatile(""
                     : "+v"(c0.x), "+v"(c0.y), "+v"(p0),
                       "+v"(c1.x), "+v"(c1.y), "+v"(p1),
                       "+v"(c2.x), "+v"(c2.y), "+v"(p2),
                       "+v"(c3.x), "+v"(c3.y), "+v"(p3));
#define RANK_ONE(J, CC, PP)                                                  \
    {                                                                        \
        const bool valid = !(CC.x < xmin || CC.x > xmax ||                   \
                             CC.y < ymin || CC.y > ymax);                    \
        const int idx = route_of(CC.x, CC.y, xmin, ymin, invx, invy);        \
        const unsigned int fixed =                                           \
            (unsigned int)(__fmul_rn(PP, FIX_SCALE) + 0.5f);                 \
        ent[kk + J] =                                                        \
            (unsigned int)(idx & (ZBAND_PIX - 1)) | (fixed << 12);           \
        const int z = idx >> 12;                                             \
        unsigned int rank = 0u;                                              \
        if (valid) rank = atomicAdd(&cnt[z], 1u);                            \
        meta[kk + J] = valid                                                 \
            ? (((unsigned int)z << 16) | rank) : 0xFFFFFFFFu;                \
    }
        RANK_ONE(0, c0, p0)
        RANK_ONE(1, c1, p1)
        RANK_ONE(2, c2, p2)
        RANK_ONE(3, c3, p3)
#undef RANK_ONE
    }
    __syncthreads();

    // reserve global arena ranges (one atomic per bin)
    if (tid < ZBANDS) {
        gbase[tid] = atomicAdd(&cursors[b * ZBANDS + tid], cnt[tid]);
    }
    __syncthreads();

    // Phase 2: store to arena at gbase[z] + block_rank
    unsigned int* ab = arena + (size_t)b * ZBANDS * ZCAP;
#pragma unroll
    for (int k = 0; k < 16; k++) {
        const unsigned int mt = meta[k];
        if (mt == 0xFFFFFFFFu) continue;
        const unsigned int z = mt >> 16;
        const unsigned int slot = gbase[z] + (mt & 0xFFFFu);
        if (slot < ZCAP) {
            ab[(size_t)z * ZCAP + slot] = ent[k];
        } else {
            // bin overflow (pathological distribution): spill globally
            const unsigned int pos = atomicAdd(spill_cnt, 1u);
            if (pos < SPILL_CAP) {
                const unsigned int e = ent[k];
                const unsigned int pix =
                    (z << 12) | (e & (ZBAND_PIX - 1));
                const float pr = __fmul_rn((float)(e >> 12), FIX_INV);
                spill[pos] = make_uint2(((unsigned int)b << 16) | pix,
                                        __float_as_uint(pr));
            }
        }
    }
}

// u32 fixed-point LDS accumulation (native ds_add_u32); 16 bands -> 512
// blocks (2/CU), 4-deep pinned uint4 loads, direct coalesced stores.
// R9: also drains the spill list (normally empty) for this (b,z).
__global__ __launch_bounds__(1024) void accum_g_kernel(
    const unsigned int* __restrict__ arena, const float* __restrict__ gia,
    const unsigned int* __restrict__ cursors, float* __restrict__ out,
    const unsigned int* __restrict__ spill_cnt,
    const uint2* __restrict__ spill) {
    __shared__ unsigned int acc[ZBAND_PIX];  // 16 KB
    const int z   = blockIdx.x;
    const int b   = blockIdx.y;
    const int tid = threadIdx.x;  // 0..1023

    // issue long-latency reads for cursor + epilogue gia before the LDS work
    const unsigned int n_raw = cursors[b * ZBANDS + z];
    const unsigned int ns_raw = *spill_cnt;
    const float4* g4 =
        (const float4*)(gia + (size_t)b * HW + (size_t)z * ZBAND_PIX);
    float4 g = g4[tid];
    asm volatile("" : "+v"(g.x), "+v"(g.y), "+v"(g.z), "+v"(g.w));

    ((uint4*)acc)[tid] = make_uint4(0u, 0u, 0u, 0u);  // 4096 words
    __syncthreads();

    unsigned int n = n_raw;
    if (n > ZCAP) n = ZCAP;
    const uint4* a4 = (const uint4*)(arena + ((size_t)b * ZBANDS + z) * ZCAP);

    // entry = fixed20<<12 | pix12 ; accumulate fixed-point pr (g factored out)
#define DO_E(w)                                                              \
    atomicAdd(&acc[(w) & (ZBAND_PIX - 1)], (w) >> 12);
    const unsigned int n4 = n >> 2;
    unsigned int j = tid;
    // typical n4 ~= 4096: every thread does exactly one 4-deep iteration
    for (; j + 3u * 1024u < n4; j += 4u * 1024u) {
        uint4 e0 = a4[j];
        uint4 e1 = a4[j + 1024u];
        uint4 e2 = a4[j + 2048u];
        uint4 e3 = a4[j + 3072u];
        // pin all 16 dwords live -> compiler must issue the 4 loads in flight
        asm volatile(""
                     : "+v"(e0.x), "+v"(e0.y), "+v"(e0.z), "+v"(e0.w),
                       "+v"(e1.x), "+v"(e1.y), "+v"(e1.z), "+v"(e1.w),
                       "+v"(e2.x), "+v"(e2.y), "+v"(e2.z), "+v"(e2.w),
                       "+v"(e3.x), "+v"(e3.y), "+v"(e3.z), "+v"(e3.w));
        DO_E(e0.x) DO_E(e0.y) DO_E(e0.z) DO_E(e0.w)
        DO_E(e1.x) DO_E(e1.y) DO_E(e1.z) DO_E(e1.w)
        DO_E(e2.x) DO_E(e2.y) DO_E(e2.z) DO_E(e2.w)
        DO_E(e3.x) DO_E(e3.y) DO_E(e3.z) DO_E(e3.w)
    }
    for (; j < n4; j += 1024u) {
        const uint4 e = a4[j];
        DO_E(e.x) DO_E(e.y) DO_E(e.z) DO_E(e.w)
    }
    const unsigned int* a1 = (const unsigned int*)a4;
    for (unsigned int jj = (n4 << 2) + tid; jj < n; jj += 1024u) {
        const unsigned int w = a1[jj];
        DO_E(w)
    }

    // fused spill drain (ns_raw is ~always 0: one uniform branch, no loop)
    if (ns_raw) {
        unsigned int ns = ns_raw;
        if (ns > SPILL_CAP) ns = SPILL_CAP;
        for (unsigned int jj = tid; jj < ns; jj += 1024u) {
            const uint2 e = spill[jj];
            const unsigned int pix = e.x & 0xFFFFu;
            if ((e.x >> 16) == (unsigned int)b &&
                (pix >> 12) == (unsigned int)z) {
                const float pr = __uint_as_float(e.y);
                const unsigned int fixed =
                    (unsigned int)(__fmul_rn(pr, FIX_SCALE) + 0.5f);
                atomicAdd(&acc[pix & (ZBAND_PIX - 1)], fixed);
            }
        }
    }
#undef DO_E
    __syncthreads();

    // out = acc * 2^-19 * g, coalesced direct store (block owns band)
    float4* o4 = (float4*)(out + (size_t)b * HW + (size_t)z * ZBAND_PIX);
    const uint4 a = ((const uint4*)acc)[tid];
    o4[tid] = make_float4(
        __fmul_rn(__fmul_rn((float)a.x, FIX_INV), g.x),
        __fmul_rn(__fmul_rn((float)a.y, FIX_INV), g.y),
        __fmul_rn(__fmul_rn((float)a.z, FIX_INV), g.z),
        __fmul_rn(__fmul_rn((float)a.w, FIX_INV), g.w));
}

// ================= FALLBACK (exact, small-ws) =================

__global__ __launch_bounds__(512) void accum_recompute_kernel(
    const float* __restrict__ point_rates, const float* __restrict__ gia,
    const float2* __restrict__ coords, const float4* __restrict__ partials,
    float* __restrict__ out) {
    __shared__ float acc[FB_BAND_PIX];
    __shared__ float4 sbox;
    const int z   = blockIdx.x;
    const int b   = blockIdx.y;
    const int tid = threadIdx.x;

    const float4 box = fold_box(partials, b, tid, &sbox);
    const float xmin = box.x, xmax = box.y, ymin = box.z, ymax = box.w;
    const float invx = __fdiv_rn(1.0f, __fsub_rn(xmax, xmin));
    const float invy = __fdiv_rn(1.0f, __fsub_rn(ymax, ymin));

    for (int j = tid; j < FB_BAND_PIX; j += 512) acc[j] = 0.f;
    __syncthreads();

    const float* prb = point_rates + (size_t)b * NSRC;
    const float* gb  = gia + (size_t)b * HW;
    const int lo = z * FB_BAND_PIX, hi = lo + FB_BAND_PIX;

    for (int i = tid; i < NSRC; i += 512) {
        const float2 c = coords[i];
        if (c.x < xmin || c.x > xmax || c.y < ymin || c.y > ymax) continue;
        const int idx = route_of(c.x, c.y, xmin, ymin, invx, invy);
        if (idx < lo || idx >= hi) continue;
        const float em = __fmul_rn(prb[i], gb[idx]);
        atomicAdd(&acc[idx - lo], em);
    }
    __syncthreads();

    float4* o4 = (float4*)(out + (size_t)b * HW + (size_t)z * FB_BAND_PIX);
    const float4* a4 = (const float4*)acc;
    for (int j = tid; j < FB_BAND_PIX / 4; j += 512) o4[j] = a4[j];
}

extern "C" void kernel_launch(void* const* d_in, const int* in_sizes, int n_in,
                              void* d_out, int out_size, void* d_ws, size_t ws_size,
                              hipStream_t stream) {
    const float* point_rates = (const float*)d_in[0];   // (B, NSRC)
    const float* spatial     = (const float*)d_in[1];   // (B, 2, H, W)
    const float* gia         = (const float*)d_in[2];   // (B, H, W)
    const float2* coords     = (const float2*)d_in[3];  // (NSRC, 2)
    float* out = (float*)d_out;                         // (B, 1, H, W)

    char* ws = (char*)d_ws;
    float4* partials = (float4*)ws;

    if (ws_size >= WS_Z_BYTES) {
        unsigned int* cursors   = (unsigned int*)(ws + WS_ZCURS_OFF);
        unsigned int* spill_cnt = (unsigned int*)(ws + WS_ZSPCNT_OFF);
        uint2*        spill     = (uint2*)(ws + WS_ZSPILL_OFF);
        unsigned int* arena     = (unsigned int*)(ws + WS_ZARENA_OFF);

        // cursors (512 u32) + spill_cnt contiguous: zero 513 u32
        box_kernel<<<dim3(NBLK, BATCH), 256, 0, stream>>>(
            spatial, partials, cursors, BATCH * ZBANDS + 1);
        scatter_lds_kernel<<<dim3(NSRC / 4096, BATCH), 256, 0, stream>>>(
            point_rates, coords, partials, cursors, arena, spill_cnt, spill);
        accum_g_kernel<<<dim3(ZBANDS, BATCH), 1024, 0, stream>>>(
            arena, gia, cursors, out, spill_cnt, spill);
    } else {
        box_kernel<<<dim3(NBLK, BATCH), 256, 0, stream>>>(
            spatial, partials, nullptr, 0);
        accum_recompute_kernel<<<dim3(FB_BANDS, BATCH), 512, 0, stream>>>(
            point_rates, gia, coords, partials, out);
    }
}